// Round 1
// baseline (4048.902 us; speedup 1.0000x reference)
//
#include <hip/hip_runtime.h>

#define N_SRC1 500000
#define N_DST1 100000
#define E1     1500000
#define N_DST2 20000
#define E2     200000
#define IN_F   128
#define H_F    256
#define N_CLS  47

// ---------------- workspace layout (floats) ----------------
// agg1 : [0,            12,800,000)   N_DST1*IN_F
// deg1 : [12,800,000,   12,900,000)   N_DST1
// agg2 : [12,900,000,   18,020,000)   N_DST2*H_F
// deg2 : [18,020,000,   18,040,000)   N_DST2
// h    : [18,040,000,   43,640,000)   N_DST1*H_F
#define OFF_AGG1 0
#define OFF_DEG1 12800000
#define OFF_AGG2 12900000
#define OFF_DEG2 18020000
#define OFF_H    18040000
#define ZERO_FLOATS 18040000   // agg1..deg2 contiguous

// ---------------- layer-1 edge scatter ----------------
// 32 lanes per edge, each lane handles a float4 (32*4 = 128 feats)
__global__ __launch_bounds__(256) void edge1_kernel(
    const float* __restrict__ x, const int* __restrict__ src,
    const int* __restrict__ dst, float* __restrict__ agg,
    float* __restrict__ deg) {
  int gid  = blockIdx.x * 256 + threadIdx.x;
  int e    = gid >> 5;
  int lane = gid & 31;
  if (e >= E1) return;
  int s = src[e];
  int d = dst[e];
  float4 v = ((const float4*)(x + (size_t)s * IN_F))[lane];
  float* a = agg + (size_t)d * IN_F + lane * 4;
  unsafeAtomicAdd(a + 0, v.x);
  unsafeAtomicAdd(a + 1, v.y);
  unsafeAtomicAdd(a + 2, v.z);
  unsafeAtomicAdd(a + 3, v.w);
  if (lane == 0) unsafeAtomicAdd(deg + d, 1.0f);
}

// ---------------- layer-1 GEMM + mean + bias + relu ----------------
// block = 256 threads = one 32-row x 256-col tile. thread t owns column t.
__global__ __launch_bounds__(256) void layer1_kernel(
    const float* __restrict__ x, const float* __restrict__ agg,
    const float* __restrict__ deg, const float* __restrict__ Ws,
    const float* __restrict__ Wn, const float* __restrict__ b,
    float* __restrict__ h) {
  __shared__ float xs[32][IN_F];
  __shared__ float ns[32][IN_F];
  __shared__ float inv[32];
  int t    = threadIdx.x;
  int row0 = blockIdx.x * 32;
  if (t < 32) inv[t] = 1.0f / fmaxf(deg[row0 + t], 1.0f);
  __syncthreads();
#pragma unroll
  for (int i = 0; i < 4; ++i) {
    int idx = t + i * 256;      // 0..1023
    int r   = idx >> 5;
    int c4  = idx & 31;
    float4 xv = ((const float4*)(x + (size_t)(row0 + r) * IN_F))[c4];
    ((float4*)&xs[r][0])[c4] = xv;
    float4 av = ((const float4*)(agg + (size_t)(row0 + r) * IN_F))[c4];
    float sc = inv[r];
    av.x *= sc; av.y *= sc; av.z *= sc; av.w *= sc;
    ((float4*)&ns[r][0])[c4] = av;
  }
  __syncthreads();

  float acc[32];
  float bj = b[t];
#pragma unroll
  for (int r = 0; r < 32; ++r) acc[r] = bj;

  for (int k = 0; k < IN_F; k += 4) {
    float4 wsv = make_float4(Ws[(k + 0) * H_F + t], Ws[(k + 1) * H_F + t],
                             Ws[(k + 2) * H_F + t], Ws[(k + 3) * H_F + t]);
    float4 wnv = make_float4(Wn[(k + 0) * H_F + t], Wn[(k + 1) * H_F + t],
                             Wn[(k + 2) * H_F + t], Wn[(k + 3) * H_F + t]);
#pragma unroll
    for (int r = 0; r < 32; ++r) {
      float4 xv = ((const float4*)&xs[r][0])[k >> 2];
      float4 nv = ((const float4*)&ns[r][0])[k >> 2];
      acc[r] += xv.x * wsv.x + xv.y * wsv.y + xv.z * wsv.z + xv.w * wsv.w;
      acc[r] += nv.x * wnv.x + nv.y * wnv.y + nv.z * wnv.z + nv.w * wnv.w;
    }
  }
#pragma unroll
  for (int r = 0; r < 32; ++r) {
    h[(size_t)(row0 + r) * H_F + t] = fmaxf(acc[r], 0.0f);
  }
}

// ---------------- layer-2 edge scatter ----------------
// 64 lanes per edge, each lane a float4 (64*4 = 256 feats)
__global__ __launch_bounds__(256) void edge2_kernel(
    const float* __restrict__ h, const int* __restrict__ src,
    const int* __restrict__ dst, float* __restrict__ agg,
    float* __restrict__ deg) {
  int gid  = blockIdx.x * 256 + threadIdx.x;
  int e    = gid >> 6;
  int lane = gid & 63;
  if (e >= E2) return;
  int s = src[e];
  int d = dst[e];
  float4 v = ((const float4*)(h + (size_t)s * H_F))[lane];
  float* a = agg + (size_t)d * H_F + lane * 4;
  unsafeAtomicAdd(a + 0, v.x);
  unsafeAtomicAdd(a + 1, v.y);
  unsafeAtomicAdd(a + 2, v.z);
  unsafeAtomicAdd(a + 3, v.w);
  if (lane == 0) unsafeAtomicAdd(deg + d, 1.0f);
}

// ---------------- layer-2 GEMM + mean + bias ----------------
// one 64-lane wave per output row; lanes 0..46 own the 47 columns.
__global__ __launch_bounds__(256) void layer2_kernel(
    const float* __restrict__ h, const float* __restrict__ agg,
    const float* __restrict__ deg, const float* __restrict__ Ws,
    const float* __restrict__ Wn, const float* __restrict__ b,
    float* __restrict__ out) {
  int gid  = blockIdx.x * 256 + threadIdx.x;
  int row  = gid >> 6;
  int lane = threadIdx.x & 63;
  if (row >= N_DST2) return;
  int j = lane < N_CLS ? lane : N_CLS - 1;  // clamp so all reads stay in-bounds
  const float* hs = h + (size_t)row * H_F;
  const float* hn = agg + (size_t)row * H_F;
  float invd = 1.0f / fmaxf(deg[row], 1.0f);
  float acc  = b[j];
  for (int kc = 0; kc < H_F; kc += 64) {
    float hv = hs[kc + lane];
    float nv = hn[kc + lane] * invd;
#pragma unroll
    for (int kk = 0; kk < 64; ++kk) {
      float a = __shfl(hv, kk, 64);
      float c = __shfl(nv, kk, 64);
      acc += a * Ws[(kc + kk) * N_CLS + j] + c * Wn[(kc + kk) * N_CLS + j];
    }
  }
  if (lane < N_CLS) out[(size_t)row * N_CLS + lane] = acc;
}

extern "C" void kernel_launch(void* const* d_in, const int* in_sizes, int n_in,
                              void* d_out, int out_size, void* d_ws, size_t ws_size,
                              hipStream_t stream) {
  const float* x   = (const float*)d_in[0];
  const float* Ws1 = (const float*)d_in[1];
  const float* Wn1 = (const float*)d_in[2];
  const float* b1  = (const float*)d_in[3];
  const float* Ws2 = (const float*)d_in[4];
  const float* Wn2 = (const float*)d_in[5];
  const float* b2  = (const float*)d_in[6];
  const int* src1  = (const int*)d_in[7];
  const int* dst1  = (const int*)d_in[8];
  const int* src2  = (const int*)d_in[9];
  const int* dst2  = (const int*)d_in[10];

  float* ws   = (float*)d_ws;
  float* agg1 = ws + OFF_AGG1;
  float* deg1 = ws + OFF_DEG1;
  float* agg2 = ws + OFF_AGG2;
  float* deg2 = ws + OFF_DEG2;
  float* h    = ws + OFF_H;
  float* out  = (float*)d_out;

  // zero the accumulators (agg1, deg1, agg2, deg2 are contiguous)
  hipMemsetAsync(ws, 0, (size_t)ZERO_FLOATS * sizeof(float), stream);

  // layer-1 edge aggregation
  {
    int blocks = (E1 * 32 + 255) / 256;
    edge1_kernel<<<blocks, 256, 0, stream>>>(x, src1, dst1, agg1, deg1);
  }
  // layer-1 dense part
  {
    int blocks = N_DST1 / 32;   // 100000/32 = 3125 exact
    layer1_kernel<<<blocks, 256, 0, stream>>>(x, agg1, deg1, Ws1, Wn1, b1, h);
  }
  // layer-2 edge aggregation
  {
    int blocks = (E2 * 64 + 255) / 256;
    edge2_kernel<<<blocks, 256, 0, stream>>>(h, src2, dst2, agg2, deg2);
  }
  // layer-2 dense part
  {
    int blocks = (N_DST2 * 64 + 255) / 256;
    layer2_kernel<<<blocks, 256, 0, stream>>>(h, agg2, deg2, Ws2, Wn2, b2, out);
  }
}

// Round 2
// 1248.732 us; speedup vs baseline: 3.2424x; 3.2424x over previous
//
#include <hip/hip_runtime.h>

#define N_SRC1 500000
#define N_DST1 100000
#define E1     1500000
#define N_DST2 20000
#define E2     200000
#define IN_F   128
#define H_F    256
#define N_CLS  47

// ---------------- workspace layout (4-byte elements) ----------------
// cnt1   [0,        100000)
// cnt2   [100000,   120000)    <- cnt1+cnt2 contiguous, one memset
// rp1    [120000,   220000)
// fill1  [220000,   320000)
// rp2    [320000,   340000)
// fill2  [340000,   360000)
// csr1   [360000,   1860000)   E1 src ids in CSR order
// csr2   [1860000,  2060000)
// agg1   [2060000,  14860000)  N_DST1*IN_F floats; agg2 ALIASES this
//                              (agg1 dead after layer1; reduce2 runs later)
// h      [14860000, 40460000)  N_DST1*H_F floats
#define OFF_CNT1  0
#define OFF_CNT2  100000
#define OFF_RP1   120000
#define OFF_FILL1 220000
#define OFF_RP2   320000
#define OFF_FILL2 340000
#define OFF_CSR1  360000
#define OFF_CSR2  1860000
#define OFF_AGG1  2060000
#define OFF_AGG2  2060000
#define OFF_H     14860000
#define ZERO_INTS 120000

// ---------------- histogram of both dst arrays ----------------
__global__ __launch_bounds__(256) void hist_kernel(
    const int* __restrict__ dst1, const int* __restrict__ dst2,
    int* __restrict__ cnt1, int* __restrict__ cnt2) {
  int i = blockIdx.x * 256 + threadIdx.x;
  if (i < E1) atomicAdd(&cnt1[dst1[i]], 1);
  if (i < E2) atomicAdd(&cnt2[dst2[i]], 1);
}

// ---------------- single-block exclusive scan (both arrays) ----------------
__device__ void scan_chunks(const int* __restrict__ cnt, int* __restrict__ rowptr,
                            int* __restrict__ fill, int n, int* wsum) {
  // wsum[0..15] = per-wave offsets, wsum[16] = running carry
  if (threadIdx.x == 0) wsum[16] = 0;
  __syncthreads();
  for (int base = 0; base < n; base += 1024) {
    int i = base + (int)threadIdx.x;
    int v = (i < n) ? cnt[i] : 0;
    int lane = threadIdx.x & 63;
    int wid  = threadIdx.x >> 6;
    int s = v;
#pragma unroll
    for (int off = 1; off < 64; off <<= 1) {
      int t = __shfl_up(s, off, 64);
      if (lane >= off) s += t;
    }
    if (lane == 63) wsum[wid] = s;
    __syncthreads();
    if (threadIdx.x == 0) {
      int run = wsum[16];
#pragma unroll
      for (int w = 0; w < 16; ++w) { int t = wsum[w]; wsum[w] = run; run += t; }
      wsum[16] = run;
    }
    __syncthreads();
    int excl = s - v + wsum[wid];
    if (i < n) { rowptr[i] = excl; fill[i] = excl; }
    __syncthreads();  // protect wsum before next chunk overwrites it
  }
}

__global__ __launch_bounds__(1024) void scan_kernel(
    const int* __restrict__ cnt1, int* __restrict__ rp1, int* __restrict__ fill1,
    const int* __restrict__ cnt2, int* __restrict__ rp2, int* __restrict__ fill2) {
  __shared__ int wsum[17];
  scan_chunks(cnt1, rp1, fill1, N_DST1, wsum);
  __syncthreads();
  scan_chunks(cnt2, rp2, fill2, N_DST2, wsum);
}

// ---------------- scatter src ids into CSR order ----------------
__global__ __launch_bounds__(256) void scatter_kernel(
    const int* __restrict__ src1, const int* __restrict__ dst1,
    const int* __restrict__ src2, const int* __restrict__ dst2,
    int* __restrict__ fill1, int* __restrict__ fill2,
    int* __restrict__ csr1, int* __restrict__ csr2) {
  int i = blockIdx.x * 256 + threadIdx.x;
  if (i < E1) {
    int p = atomicAdd(&fill1[dst1[i]], 1);
    csr1[p] = src1[i];
  }
  if (i < E2) {
    int p = atomicAdd(&fill2[dst2[i]], 1);
    csr2[p] = src2[i];
  }
}

// ---------------- layer-1 gather-reduce: one wave per dst ----------------
// lanes 0-31 handle even edges, 32-63 odd edges; each half covers 128 feats
__global__ __launch_bounds__(256) void reduce1_kernel(
    const float* __restrict__ x, const int* __restrict__ csr,
    const int* __restrict__ rowptr, const int* __restrict__ cnt,
    float* __restrict__ agg) {
  int w = (blockIdx.x * 256 + threadIdx.x) >> 6;
  if (w >= N_DST1) return;
  int lane = threadIdx.x & 63;
  int slot = lane >> 5;
  int f4   = lane & 31;
  int start = rowptr[w];
  int n     = cnt[w];
  float4 acc = make_float4(0.f, 0.f, 0.f, 0.f);
  for (int j = slot; j < n; j += 2) {
    int s = csr[start + j];
    float4 v = ((const float4*)(x + (size_t)s * IN_F))[f4];
    acc.x += v.x; acc.y += v.y; acc.z += v.z; acc.w += v.w;
  }
  // combine the two edge-slots
  acc.x += __shfl(acc.x, lane ^ 32, 64);
  acc.y += __shfl(acc.y, lane ^ 32, 64);
  acc.z += __shfl(acc.z, lane ^ 32, 64);
  acc.w += __shfl(acc.w, lane ^ 32, 64);
  if (lane < 32) ((float4*)(agg + (size_t)w * IN_F))[f4] = acc;
}

// ---------------- layer-1 GEMM + mean + bias + relu ----------------
__global__ __launch_bounds__(256) void layer1_kernel(
    const float* __restrict__ x, const float* __restrict__ agg,
    const int* __restrict__ cnt, const float* __restrict__ Ws,
    const float* __restrict__ Wn, const float* __restrict__ b,
    float* __restrict__ h) {
  __shared__ float xs[32][IN_F];
  __shared__ float ns[32][IN_F];
  __shared__ float inv[32];
  int t    = threadIdx.x;
  int row0 = blockIdx.x * 32;
  if (t < 32) inv[t] = 1.0f / fmaxf((float)cnt[row0 + t], 1.0f);
  __syncthreads();
#pragma unroll
  for (int i = 0; i < 4; ++i) {
    int idx = t + i * 256;
    int r   = idx >> 5;
    int c4  = idx & 31;
    float4 xv = ((const float4*)(x + (size_t)(row0 + r) * IN_F))[c4];
    ((float4*)&xs[r][0])[c4] = xv;
    float4 av = ((const float4*)(agg + (size_t)(row0 + r) * IN_F))[c4];
    float sc = inv[r];
    av.x *= sc; av.y *= sc; av.z *= sc; av.w *= sc;
    ((float4*)&ns[r][0])[c4] = av;
  }
  __syncthreads();

  float acc[32];
  float bj = b[t];
#pragma unroll
  for (int r = 0; r < 32; ++r) acc[r] = bj;

  for (int k = 0; k < IN_F; k += 4) {
    float4 wsv = make_float4(Ws[(k + 0) * H_F + t], Ws[(k + 1) * H_F + t],
                             Ws[(k + 2) * H_F + t], Ws[(k + 3) * H_F + t]);
    float4 wnv = make_float4(Wn[(k + 0) * H_F + t], Wn[(k + 1) * H_F + t],
                             Wn[(k + 2) * H_F + t], Wn[(k + 3) * H_F + t]);
#pragma unroll
    for (int r = 0; r < 32; ++r) {
      float4 xv = ((const float4*)&xs[r][0])[k >> 2];
      float4 nv = ((const float4*)&ns[r][0])[k >> 2];
      acc[r] += xv.x * wsv.x + xv.y * wsv.y + xv.z * wsv.z + xv.w * wsv.w;
      acc[r] += nv.x * wnv.x + nv.y * wnv.y + nv.z * wnv.z + nv.w * wnv.w;
    }
  }
#pragma unroll
  for (int r = 0; r < 32; ++r) {
    h[(size_t)(row0 + r) * H_F + t] = fmaxf(acc[r], 0.0f);
  }
}

// ---------------- layer-2 gather-reduce: one wave per dst ----------------
// 64 lanes x float4 = 256 feats, one edge per iteration
__global__ __launch_bounds__(256) void reduce2_kernel(
    const float* __restrict__ h, const int* __restrict__ csr,
    const int* __restrict__ rowptr, const int* __restrict__ cnt,
    float* __restrict__ agg) {
  int w = (blockIdx.x * 256 + threadIdx.x) >> 6;
  if (w >= N_DST2) return;
  int lane = threadIdx.x & 63;
  int start = rowptr[w];
  int n     = cnt[w];
  float4 acc = make_float4(0.f, 0.f, 0.f, 0.f);
  for (int j = 0; j < n; ++j) {
    int s = csr[start + j];
    float4 v = ((const float4*)(h + (size_t)s * H_F))[lane];
    acc.x += v.x; acc.y += v.y; acc.z += v.z; acc.w += v.w;
  }
  ((float4*)(agg + (size_t)w * H_F))[lane] = acc;
}

// ---------------- layer-2 GEMM + mean + bias ----------------
__global__ __launch_bounds__(256) void layer2_kernel(
    const float* __restrict__ h, const float* __restrict__ agg,
    const int* __restrict__ cnt, const float* __restrict__ Ws,
    const float* __restrict__ Wn, const float* __restrict__ b,
    float* __restrict__ out) {
  int gid  = blockIdx.x * 256 + threadIdx.x;
  int row  = gid >> 6;
  int lane = threadIdx.x & 63;
  if (row >= N_DST2) return;
  int j = lane < N_CLS ? lane : N_CLS - 1;
  const float* hs = h + (size_t)row * H_F;
  const float* hn = agg + (size_t)row * H_F;
  float invd = 1.0f / fmaxf((float)cnt[row], 1.0f);
  float acc  = b[j];
  for (int kc = 0; kc < H_F; kc += 64) {
    float hv = hs[kc + lane];
    float nv = hn[kc + lane] * invd;
#pragma unroll
    for (int kk = 0; kk < 64; ++kk) {
      float a = __shfl(hv, kk, 64);
      float c = __shfl(nv, kk, 64);
      acc += a * Ws[(kc + kk) * N_CLS + j] + c * Wn[(kc + kk) * N_CLS + j];
    }
  }
  if (lane < N_CLS) out[(size_t)row * N_CLS + lane] = acc;
}

extern "C" void kernel_launch(void* const* d_in, const int* in_sizes, int n_in,
                              void* d_out, int out_size, void* d_ws, size_t ws_size,
                              hipStream_t stream) {
  const float* x   = (const float*)d_in[0];
  const float* Ws1 = (const float*)d_in[1];
  const float* Wn1 = (const float*)d_in[2];
  const float* b1  = (const float*)d_in[3];
  const float* Ws2 = (const float*)d_in[4];
  const float* Wn2 = (const float*)d_in[5];
  const float* b2  = (const float*)d_in[6];
  const int* src1  = (const int*)d_in[7];
  const int* dst1  = (const int*)d_in[8];
  const int* src2  = (const int*)d_in[9];
  const int* dst2  = (const int*)d_in[10];

  int*   wsI  = (int*)d_ws;
  float* wsF  = (float*)d_ws;
  int*   cnt1  = wsI + OFF_CNT1;
  int*   cnt2  = wsI + OFF_CNT2;
  int*   rp1   = wsI + OFF_RP1;
  int*   fill1 = wsI + OFF_FILL1;
  int*   rp2   = wsI + OFF_RP2;
  int*   fill2 = wsI + OFF_FILL2;
  int*   csr1  = wsI + OFF_CSR1;
  int*   csr2  = wsI + OFF_CSR2;
  float* agg1  = wsF + OFF_AGG1;
  float* agg2  = wsF + OFF_AGG2;   // aliases agg1 (agg1 dead after layer1)
  float* h     = wsF + OFF_H;
  float* out   = (float*)d_out;

  hipMemsetAsync(wsI, 0, (size_t)ZERO_INTS * sizeof(int), stream);

  {
    int blocks = (E1 + 255) / 256;
    hist_kernel<<<blocks, 256, 0, stream>>>(dst1, dst2, cnt1, cnt2);
  }
  scan_kernel<<<1, 1024, 0, stream>>>(cnt1, rp1, fill1, cnt2, rp2, fill2);
  {
    int blocks = (E1 + 255) / 256;
    scatter_kernel<<<blocks, 256, 0, stream>>>(src1, dst1, src2, dst2,
                                               fill1, fill2, csr1, csr2);
  }
  {
    int blocks = (N_DST1 * 64 + 255) / 256;
    reduce1_kernel<<<blocks, 256, 0, stream>>>(x, csr1, rp1, cnt1, agg1);
  }
  layer1_kernel<<<N_DST1 / 32, 256, 0, stream>>>(x, agg1, cnt1, Ws1, Wn1, b1, h);
  {
    int blocks = (N_DST2 * 64 + 255) / 256;
    reduce2_kernel<<<blocks, 256, 0, stream>>>(h, csr2, rp2, cnt2, agg2);
  }
  {
    int blocks = (N_DST2 * 64 + 255) / 256;
    layer2_kernel<<<blocks, 256, 0, stream>>>(h, agg2, cnt2, Ws2, Wn2, b2, out);
  }
}

// Round 5
// 947.741 us; speedup vs baseline: 4.2722x; 1.3176x over previous
//
#include <hip/hip_runtime.h>

#define N_SRC1 500000
#define N_DST1 100000
#define E1     1500000
#define N_DST2 20000
#define E2     200000
#define IN_F   128
#define H_F    256
#define N_CLS  47
#define NTOT   120000        // cnt1 ++ cnt2 scanned as one array (sum(cnt1)=E1)
#define NB_SCAN 118          // ceil(120000/1024)

// ---------------- workspace layout (4-byte elements) ----------------
#define OFF_CNT1  0
#define OFF_CNT2  100000     // contiguous with cnt1
#define OFF_RP1   120000
#define OFF_RP2   220000
#define OFF_FILL1 240000
#define OFF_FILL2 340000
#define OFF_PART  360000     // 128 ints of scan partials
#define OFF_WT1   360256     // 32768 ints = 256x256 bf16 transposed [n][k]
#define OFF_CSR1  393024
#define OFF_CSR2  1893024
#define OFF_AGG1  2093024    // N_DST1*IN_F floats; agg2 aliases (agg1 dead after layer1)
#define OFF_H     14893024   // N_DST1*H_F floats   (total 161.97 MB)
#define ZERO_INTS 120000

typedef __attribute__((ext_vector_type(8))) short short8;
typedef __attribute__((ext_vector_type(4))) float floatx4;

static __device__ inline unsigned short f2bf(float f) {
  union { float f; unsigned u; } v; v.f = f;
  unsigned r = v.u + 0x7FFF + ((v.u >> 16) & 1);   // round-to-nearest-even
  return (unsigned short)(r >> 16);
}

// ---------------- histogram of both dst arrays ----------------
__global__ __launch_bounds__(256) void hist_kernel(
    const int* __restrict__ dst1, const int* __restrict__ dst2,
    int* __restrict__ cnt1, int* __restrict__ cnt2) {
  int i = blockIdx.x * 256 + threadIdx.x;
  if (i < E1) atomicAdd(&cnt1[dst1[i]], 1);
  if (i < E2) atomicAdd(&cnt2[dst2[i]], 1);
}

// ---------------- multi-block exclusive scan over cnt1++cnt2 ----------------
__global__ __launch_bounds__(1024) void scanA_kernel(
    const int* __restrict__ cnt, int* __restrict__ part) {
  __shared__ int wsum[16];
  int i = blockIdx.x * 1024 + threadIdx.x;
  int v = (i < NTOT) ? cnt[i] : 0;
  int lane = threadIdx.x & 63, wid = threadIdx.x >> 6;
#pragma unroll
  for (int off = 1; off < 64; off <<= 1) v += __shfl_xor(v, off, 64);
  if (lane == 0) wsum[wid] = v;
  __syncthreads();
  if (threadIdx.x == 0) {
    int s = 0;
#pragma unroll
    for (int w = 0; w < 16; ++w) s += wsum[w];
    part[blockIdx.x] = s;
  }
}

__global__ __launch_bounds__(64) void scanB_kernel(int* __restrict__ part) {
  if (threadIdx.x == 0) {
    int run = 0;
    for (int i = 0; i < NB_SCAN; ++i) { int t = part[i]; part[i] = run; run += t; }
  }
}

__global__ __launch_bounds__(1024) void scanC_kernel(
    const int* __restrict__ cnt, const int* __restrict__ part,
    int* __restrict__ rp1, int* __restrict__ rp2,
    int* __restrict__ fill1, int* __restrict__ fill2) {
  __shared__ int wsum[16];
  int i = blockIdx.x * 1024 + threadIdx.x;
  int v = (i < NTOT) ? cnt[i] : 0;
  int lane = threadIdx.x & 63, wid = threadIdx.x >> 6;
  int s = v;
#pragma unroll
  for (int off = 1; off < 64; off <<= 1) {
    int t = __shfl_up(s, off, 64);
    if (lane >= off) s += t;
  }
  if (lane == 63) wsum[wid] = s;
  __syncthreads();
  if (threadIdx.x == 0) {
    int run = part[blockIdx.x];
#pragma unroll
    for (int w = 0; w < 16; ++w) { int t = wsum[w]; wsum[w] = run; run += t; }
  }
  __syncthreads();
  int excl = s - v + wsum[wid];
  if (i < N_DST1)      { rp1[i] = excl;          fill1[i] = excl; }
  else if (i < NTOT)   { rp2[i - N_DST1] = excl - E1; fill2[i - N_DST1] = excl - E1; }
}

// ---------------- scatter src ids into CSR order ----------------
__global__ __launch_bounds__(256) void scatter_kernel(
    const int* __restrict__ src1, const int* __restrict__ dst1,
    const int* __restrict__ src2, const int* __restrict__ dst2,
    int* __restrict__ fill1, int* __restrict__ fill2,
    int* __restrict__ csr1, int* __restrict__ csr2) {
  int i = blockIdx.x * 256 + threadIdx.x;
  if (i < E1) {
    int p = atomicAdd(&fill1[dst1[i]], 1);
    csr1[p] = src1[i];
  }
  if (i < E2) {
    int p = atomicAdd(&fill2[dst2[i]], 1);
    csr2[p] = src2[i];
  }
}

// ---------------- W1 transpose+convert: Wt[n][k] bf16, k = [Ws1;Wn1] ----------------
__global__ __launch_bounds__(256) void convw_kernel(
    const float* __restrict__ Ws, const float* __restrict__ Wn,
    unsigned short* __restrict__ Wt) {
  int n = blockIdx.x;     // 0..255
  int k = threadIdx.x;    // 0..255
  float v = (k < IN_F) ? Ws[k * H_F + n] : Wn[(k - IN_F) * H_F + n];
  Wt[n * 256 + k] = f2bf(v);
}

// ---------------- layer-1 gather-reduce: one wave per dst ----------------
__global__ __launch_bounds__(256) void reduce1_kernel(
    const float* __restrict__ x, const int* __restrict__ csr,
    const int* __restrict__ rowptr, const int* __restrict__ cnt,
    float* __restrict__ agg) {
  int w = (blockIdx.x * 256 + threadIdx.x) >> 6;
  if (w >= N_DST1) return;
  int lane = threadIdx.x & 63;
  int slot = lane >> 5;
  int f4   = lane & 31;
  int start = rowptr[w];
  int n     = cnt[w];
  float4 acc = make_float4(0.f, 0.f, 0.f, 0.f);
  for (int j = slot; j < n; j += 2) {
    int s = csr[start + j];
    float4 v = ((const float4*)(x + (size_t)s * IN_F))[f4];
    acc.x += v.x; acc.y += v.y; acc.z += v.z; acc.w += v.w;
  }
  acc.x += __shfl(acc.x, lane ^ 32, 64);
  acc.y += __shfl(acc.y, lane ^ 32, 64);
  acc.z += __shfl(acc.z, lane ^ 32, 64);
  acc.w += __shfl(acc.w, lane ^ 32, 64);
  if (lane < 32) ((float4*)(agg + (size_t)w * IN_F))[f4] = acc;
}

// ---------------- layer-1 MFMA GEMM: h = relu([x|agg/deg] @ [Ws;Wn] + b) ----------------
// block = 256 thr = 4 waves; tile M=64, N=256 (wave w owns cols 64w..64w+63)
#define ASTR 264   // A row stride in ushorts (256 + 8 pad -> 2-way banks, free)
#define WSTR 40    // W chunk row stride in ushorts (32 + 8 pad)
__global__ __launch_bounds__(256) void layer1_mfma_kernel(
    const float* __restrict__ x, const float* __restrict__ agg,
    const int* __restrict__ cnt, const unsigned short* __restrict__ Wt,
    const float* __restrict__ b, float* __restrict__ h) {
  __shared__ __align__(16) unsigned short As[64 * ASTR];   // 33.0 KB, 16B-aligned base
  __shared__ __align__(16) unsigned short Wl[256 * WSTR];  // 20.0 KB, 16B-aligned base
  __shared__ float inv[64];
  int t    = threadIdx.x;
  int row0 = blockIdx.x * 64;
  if (t < 64) {
    int gr = row0 + t;
    float d = (gr < N_DST1) ? (float)cnt[gr] : 1.f;
    inv[t] = 1.f / fmaxf(d, 1.f);
  }
  __syncthreads();
  // stage A = [x | agg*inv] as bf16, row-major [64][256] (+pad)
#pragma unroll
  for (int i = 0; i < 8; ++i) {
    int g = t + i * 256;          // 0..2047
    int r = g >> 5, seg = g & 31, k0 = seg * 8;
    int grow = row0 + r;
    float4 v0, v1; float sc;
    if (grow < N_DST1) {
      const float* src = (k0 < IN_F) ? (x + (size_t)grow * IN_F + k0)
                                     : (agg + (size_t)grow * IN_F + (k0 - IN_F));
      sc = (k0 < IN_F) ? 1.f : inv[r];
      v0 = ((const float4*)src)[0];
      v1 = ((const float4*)src)[1];
    } else {
      v0 = v1 = make_float4(0.f, 0.f, 0.f, 0.f); sc = 1.f;
    }
    uint4 p;
    p.x = (unsigned)f2bf(v0.x * sc) | ((unsigned)f2bf(v0.y * sc) << 16);
    p.y = (unsigned)f2bf(v0.z * sc) | ((unsigned)f2bf(v0.w * sc) << 16);
    p.z = (unsigned)f2bf(v1.x * sc) | ((unsigned)f2bf(v1.y * sc) << 16);
    p.w = (unsigned)f2bf(v1.z * sc) | ((unsigned)f2bf(v1.w * sc) << 16);
    *((uint4*)(As + r * ASTR + seg * 8)) = p;   // byte off = r*528 + seg*16, 16B aligned
  }

  floatx4 acc[4][4] = {};
  int wid = t >> 6, lane = t & 63;
  int quad = lane >> 4, l15 = lane & 15;

  for (int kc = 0; kc < 8; ++kc) {
    int k0 = kc * 32;
    __syncthreads();   // prior readers done (also orders A staging on kc==0)
    // stage W chunk: Wl[n][0..31] = Wt[n][k0..k0+31]  (already bf16, plain copy)
#pragma unroll
    for (int rep = 0; rep < 4; ++rep) {
      int flat = t + rep * 256;     // 0..1023
      int n = flat >> 2, part = flat & 3;
      *((uint4*)(Wl + n * WSTR + part * 8)) =
          *((const uint4*)(Wt + n * 256 + k0 + part * 8));
    }
    __syncthreads();
    short8 af[4], bfr[4];
#pragma unroll
    for (int mi = 0; mi < 4; ++mi)
      af[mi] = *((const short8*)(As + (mi * 16 + l15) * ASTR + k0 + quad * 8));
#pragma unroll
    for (int ni = 0; ni < 4; ++ni)
      bfr[ni] = *((const short8*)(Wl + (wid * 64 + ni * 16 + l15) * WSTR + quad * 8));
#pragma unroll
    for (int mi = 0; mi < 4; ++mi)
#pragma unroll
      for (int ni = 0; ni < 4; ++ni)
        acc[mi][ni] = __builtin_amdgcn_mfma_f32_16x16x32_bf16(
            af[mi], bfr[ni], acc[mi][ni], 0, 0, 0);
  }

  // epilogue: C/D map col=lane&15, row=quad*4+reg
  float bv[4];
#pragma unroll
  for (int ni = 0; ni < 4; ++ni) bv[ni] = b[wid * 64 + ni * 16 + l15];
#pragma unroll
  for (int mi = 0; mi < 4; ++mi) {
    int rbase = row0 + mi * 16 + quad * 4;
#pragma unroll
    for (int r = 0; r < 4; ++r) {
      int row = rbase + r;
      if (row < N_DST1) {
#pragma unroll
        for (int ni = 0; ni < 4; ++ni)
          h[(size_t)row * H_F + wid * 64 + ni * 16 + l15] =
              fmaxf(acc[mi][ni][r] + bv[ni], 0.f);
      }
    }
  }
}

// ---------------- layer-2 gather-reduce: one wave per dst ----------------
__global__ __launch_bounds__(256) void reduce2_kernel(
    const float* __restrict__ h, const int* __restrict__ csr,
    const int* __restrict__ rowptr, const int* __restrict__ cnt,
    float* __restrict__ agg) {
  int w = (blockIdx.x * 256 + threadIdx.x) >> 6;
  if (w >= N_DST2) return;
  int lane = threadIdx.x & 63;
  int start = rowptr[w];
  int n     = cnt[w];
  float4 acc = make_float4(0.f, 0.f, 0.f, 0.f);
  for (int j = 0; j < n; ++j) {
    int s = csr[start + j];
    float4 v = ((const float4*)(h + (size_t)s * H_F))[lane];
    acc.x += v.x; acc.y += v.y; acc.z += v.z; acc.w += v.w;
  }
  ((float4*)(agg + (size_t)w * H_F))[lane] = acc;
}

// ---------------- layer-2 GEMM + mean + bias ----------------
__global__ __launch_bounds__(256) void layer2_kernel(
    const float* __restrict__ h, const float* __restrict__ agg,
    const int* __restrict__ cnt, const float* __restrict__ Ws,
    const float* __restrict__ Wn, const float* __restrict__ b,
    float* __restrict__ out) {
  int gid  = blockIdx.x * 256 + threadIdx.x;
  int row  = gid >> 6;
  int lane = threadIdx.x & 63;
  if (row >= N_DST2) return;
  int j = lane < N_CLS ? lane : N_CLS - 1;
  const float* hs = h + (size_t)row * H_F;
  const float* hn = agg + (size_t)row * H_F;
  float invd = 1.0f / fmaxf((float)cnt[row], 1.0f);
  float acc  = b[j];
  for (int kc = 0; kc < H_F; kc += 64) {
    float hv = hs[kc + lane];
    float nv = hn[kc + lane] * invd;
#pragma unroll
    for (int kk = 0; kk < 64; ++kk) {
      float a = __shfl(hv, kk, 64);
      float c = __shfl(nv, kk, 64);
      acc += a * Ws[(kc + kk) * N_CLS + j] + c * Wn[(kc + kk) * N_CLS + j];
    }
  }
  if (lane < N_CLS) out[(size_t)row * N_CLS + lane] = acc;
}

extern "C" void kernel_launch(void* const* d_in, const int* in_sizes, int n_in,
                              void* d_out, int out_size, void* d_ws, size_t ws_size,
                              hipStream_t stream) {
  const float* x   = (const float*)d_in[0];
  const float* Ws1 = (const float*)d_in[1];
  const float* Wn1 = (const float*)d_in[2];
  const float* b1  = (const float*)d_in[3];
  const float* Ws2 = (const float*)d_in[4];
  const float* Wn2 = (const float*)d_in[5];
  const float* b2  = (const float*)d_in[6];
  const int* src1  = (const int*)d_in[7];
  const int* dst1  = (const int*)d_in[8];
  const int* src2  = (const int*)d_in[9];
  const int* dst2  = (const int*)d_in[10];

  int*   wsI  = (int*)d_ws;
  float* wsF  = (float*)d_ws;
  int*   cnt1  = wsI + OFF_CNT1;
  int*   cnt2  = wsI + OFF_CNT2;
  int*   rp1   = wsI + OFF_RP1;
  int*   rp2   = wsI + OFF_RP2;
  int*   fill1 = wsI + OFF_FILL1;
  int*   fill2 = wsI + OFF_FILL2;
  int*   part  = wsI + OFF_PART;
  unsigned short* Wt = (unsigned short*)(wsI + OFF_WT1);
  int*   csr1  = wsI + OFF_CSR1;
  int*   csr2  = wsI + OFF_CSR2;
  float* agg1  = wsF + OFF_AGG1;
  float* agg2  = wsF + OFF_AGG1;   // aliases agg1 (agg1 dead after layer1)
  float* h     = wsF + OFF_H;
  float* out   = (float*)d_out;

  hipMemsetAsync(wsI, 0, (size_t)ZERO_INTS * sizeof(int), stream);

  {
    int blocks = (E1 + 255) / 256;
    hist_kernel<<<blocks, 256, 0, stream>>>(dst1, dst2, cnt1, cnt2);
  }
  scanA_kernel<<<NB_SCAN, 1024, 0, stream>>>(cnt1, part);
  scanB_kernel<<<1, 64, 0, stream>>>(part);
  scanC_kernel<<<NB_SCAN, 1024, 0, stream>>>(cnt1, part, rp1, rp2, fill1, fill2);
  {
    int blocks = (E1 + 255) / 256;
    scatter_kernel<<<blocks, 256, 0, stream>>>(src1, dst1, src2, dst2,
                                               fill1, fill2, csr1, csr2);
  }
  convw_kernel<<<256, 256, 0, stream>>>(Ws1, Wn1, Wt);
  {
    int blocks = (N_DST1 * 64 + 255) / 256;
    reduce1_kernel<<<blocks, 256, 0, stream>>>(x, csr1, rp1, cnt1, agg1);
  }
  {
    int blocks = (N_DST1 + 63) / 64;   // 1563
    layer1_mfma_kernel<<<blocks, 256, 0, stream>>>(x, agg1, cnt1, Wt, b1, h);
  }
  {
    int blocks = (N_DST2 * 64 + 255) / 256;
    reduce2_kernel<<<blocks, 256, 0, stream>>>(h, csr2, rp2, cnt2, agg2);
  }
  {
    int blocks = (N_DST2 * 64 + 255) / 256;
    layer2_kernel<<<blocks, 256, 0, stream>>>(h, agg2, cnt2, Ws2, Wn2, b2, out);
  }
}

// Round 7
// 768.620 us; speedup vs baseline: 5.2678x; 1.2330x over previous
//
#include <hip/hip_runtime.h>

#define N_SRC1 500000
#define N_DST1 100000
#define E1     1500000
#define N_DST2 20000
#define E2     200000
#define IN_F   128
#define H_F    256
#define N_CLS  47
#define NTOT   120000        // cnt1 ++ cnt2 scanned as one array (sum(cnt1)=E1)
#define NB_SCAN 118          // ceil(120000/1024)

// ---------------- workspace layout (4-byte elements) ----------------
#define OFF_CNT1  0
#define OFF_CNT2  100000     // contiguous with cnt1
#define OFF_RP1   120000
#define OFF_RP2   220000
#define OFF_FILL1 240000
#define OFF_FILL2 340000
#define OFF_PART  360000     // 128 ints of scan partials
#define OFF_WT1   360256     // 32768 ints = 256x256 bf16 [n][k], k=[Ws1;Wn1]
#define OFF_WT2   393024     // 24576 ints = 48x512 bf16 [n][k], k=[Ws2;Wn2]
#define OFF_CSR1  417600
#define OFF_CSR2  1917600
#define OFF_AGG1  2117600    // N_DST1*IN_F floats; agg2 aliases (agg1 dead after layer1)
#define OFF_H     14917600   // N_DST1*H_F bf16 = 12.8M ints   (total ~110.9 MB)
#define ZERO_INTS 120000

typedef __attribute__((ext_vector_type(8))) short short8;
typedef __attribute__((ext_vector_type(4))) float floatx4;

static __device__ inline unsigned short f2bf(float f) {
  union { float f; unsigned u; } v; v.f = f;
  unsigned r = v.u + 0x7FFF + ((v.u >> 16) & 1);   // round-to-nearest-even
  return (unsigned short)(r >> 16);
}
static __device__ inline float bf2f(unsigned short u) {
  union { unsigned u; float f; } v; v.u = ((unsigned)u) << 16;
  return v.f;
}

// ---------------- histogram of both dst arrays ----------------
__global__ __launch_bounds__(256) void hist_kernel(
    const int* __restrict__ dst1, const int* __restrict__ dst2,
    int* __restrict__ cnt1, int* __restrict__ cnt2) {
  int i = blockIdx.x * 256 + threadIdx.x;
  if (i < E1) atomicAdd(&cnt1[dst1[i]], 1);
  if (i < E2) atomicAdd(&cnt2[dst2[i]], 1);
}

// ---------------- multi-block exclusive scan over cnt1++cnt2 ----------------
__global__ __launch_bounds__(1024) void scanA_kernel(
    const int* __restrict__ cnt, int* __restrict__ part) {
  __shared__ int wsum[16];
  int i = blockIdx.x * 1024 + threadIdx.x;
  int v = (i < NTOT) ? cnt[i] : 0;
  int lane = threadIdx.x & 63, wid = threadIdx.x >> 6;
#pragma unroll
  for (int off = 1; off < 64; off <<= 1) v += __shfl_xor(v, off, 64);
  if (lane == 0) wsum[wid] = v;
  __syncthreads();
  if (threadIdx.x == 0) {
    int s = 0;
#pragma unroll
    for (int w = 0; w < 16; ++w) s += wsum[w];
    part[blockIdx.x] = s;
  }
}

__global__ __launch_bounds__(64) void scanB_kernel(int* __restrict__ part) {
  if (threadIdx.x == 0) {
    int run = 0;
    for (int i = 0; i < NB_SCAN; ++i) { int t = part[i]; part[i] = run; run += t; }
  }
}

__global__ __launch_bounds__(1024) void scanC_kernel(
    const int* __restrict__ cnt, const int* __restrict__ part,
    int* __restrict__ rp1, int* __restrict__ rp2,
    int* __restrict__ fill1, int* __restrict__ fill2) {
  __shared__ int wsum[16];
  int i = blockIdx.x * 1024 + threadIdx.x;
  int v = (i < NTOT) ? cnt[i] : 0;
  int lane = threadIdx.x & 63, wid = threadIdx.x >> 6;
  int s = v;
#pragma unroll
  for (int off = 1; off < 64; off <<= 1) {
    int t = __shfl_up(s, off, 64);
    if (lane >= off) s += t;
  }
  if (lane == 63) wsum[wid] = s;
  __syncthreads();
  if (threadIdx.x == 0) {
    int run = part[blockIdx.x];
#pragma unroll
    for (int w = 0; w < 16; ++w) { int t = wsum[w]; wsum[w] = run; run += t; }
  }
  __syncthreads();
  int excl = s - v + wsum[wid];
  if (i < N_DST1)      { rp1[i] = excl;          fill1[i] = excl; }
  else if (i < NTOT)   { rp2[i - N_DST1] = excl - E1; fill2[i - N_DST1] = excl - E1; }
}

// ---------------- scatter src ids into CSR order ----------------
__global__ __launch_bounds__(256) void scatter_kernel(
    const int* __restrict__ src1, const int* __restrict__ dst1,
    const int* __restrict__ src2, const int* __restrict__ dst2,
    int* __restrict__ fill1, int* __restrict__ fill2,
    int* __restrict__ csr1, int* __restrict__ csr2) {
  int i = blockIdx.x * 256 + threadIdx.x;
  if (i < E1) {
    int p = atomicAdd(&fill1[dst1[i]], 1);
    csr1[p] = src1[i];
  }
  if (i < E2) {
    int p = atomicAdd(&fill2[dst2[i]], 1);
    csr2[p] = src2[i];
  }
}

// ---------------- W1 transpose+convert: Wt[n][k] bf16, k = [Ws1;Wn1] ----------------
__global__ __launch_bounds__(256) void convw_kernel(
    const float* __restrict__ Ws, const float* __restrict__ Wn,
    unsigned short* __restrict__ Wt) {
  int n = blockIdx.x;     // 0..255
  int k = threadIdx.x;    // 0..255
  float v = (k < IN_F) ? Ws[k * H_F + n] : Wn[(k - IN_F) * H_F + n];
  Wt[n * 256 + k] = f2bf(v);
}

// ---------------- W2 transpose+convert: Wt2[n][k] bf16 (n padded to 48) ----------------
__global__ __launch_bounds__(512) void convw2_kernel(
    const float* __restrict__ Ws, const float* __restrict__ Wn,
    unsigned short* __restrict__ Wt2) {
  int n = blockIdx.x;     // 0..47
  int k = threadIdx.x;    // 0..511
  float v = 0.f;
  if (n < N_CLS) v = (k < H_F) ? Ws[k * N_CLS + n] : Wn[(k - H_F) * N_CLS + n];
  Wt2[n * 512 + k] = f2bf(v);
}

// ---------------- layer-1 gather-reduce: one wave per dst ----------------
__global__ __launch_bounds__(256) void reduce1_kernel(
    const float* __restrict__ x, const int* __restrict__ csr,
    const int* __restrict__ rowptr, const int* __restrict__ cnt,
    float* __restrict__ agg) {
  int w = (blockIdx.x * 256 + threadIdx.x) >> 6;
  if (w >= N_DST1) return;
  int lane = threadIdx.x & 63;
  int slot = lane >> 5;
  int f4   = lane & 31;
  int start = rowptr[w];
  int n     = cnt[w];
  float4 acc = make_float4(0.f, 0.f, 0.f, 0.f);
  for (int j = slot; j < n; j += 2) {
    int s = csr[start + j];
    float4 v = ((const float4*)(x + (size_t)s * IN_F))[f4];
    acc.x += v.x; acc.y += v.y; acc.z += v.z; acc.w += v.w;
  }
  acc.x += __shfl(acc.x, lane ^ 32, 64);
  acc.y += __shfl(acc.y, lane ^ 32, 64);
  acc.z += __shfl(acc.z, lane ^ 32, 64);
  acc.w += __shfl(acc.w, lane ^ 32, 64);
  if (lane < 32) ((float4*)(agg + (size_t)w * IN_F))[f4] = acc;
}

// ---------------- layer-1 MFMA GEMM: h = relu([x|agg/deg] @ [Ws;Wn] + b), h bf16 ---
// block = 256 thr = 4 waves; tile M=64, N=256 (wave w owns cols 64w..64w+63)
#define ASTR 264   // A row stride in ushorts (256 + 8 pad -> 2-way banks, free)
#define WSTR 40    // W chunk row stride in ushorts (32 + 8 pad)
__global__ __launch_bounds__(256) void layer1_mfma_kernel(
    const float* __restrict__ x, const float* __restrict__ agg,
    const int* __restrict__ cnt, const unsigned short* __restrict__ Wt,
    const float* __restrict__ b, unsigned short* __restrict__ h) {
  __shared__ __align__(16) unsigned short As[64 * ASTR];   // 33.0 KB
  __shared__ __align__(16) unsigned short Wl[256 * WSTR];  // 20.0 KB
  __shared__ float inv[64];
  int t    = threadIdx.x;
  int row0 = blockIdx.x * 64;
  if (t < 64) {
    int gr = row0 + t;
    float d = (gr < N_DST1) ? (float)cnt[gr] : 1.f;
    inv[t] = 1.f / fmaxf(d, 1.f);
  }
  __syncthreads();
  // stage A = [x | agg*inv] as bf16, row-major [64][256] (+pad)
#pragma unroll
  for (int i = 0; i < 8; ++i) {
    int g = t + i * 256;          // 0..2047
    int r = g >> 5, seg = g & 31, k0 = seg * 8;
    int grow = row0 + r;
    float4 v0, v1; float sc;
    if (grow < N_DST1) {
      const float* src = (k0 < IN_F) ? (x + (size_t)grow * IN_F + k0)
                                     : (agg + (size_t)grow * IN_F + (k0 - IN_F));
      sc = (k0 < IN_F) ? 1.f : inv[r];
      v0 = ((const float4*)src)[0];
      v1 = ((const float4*)src)[1];
    } else {
      v0 = v1 = make_float4(0.f, 0.f, 0.f, 0.f); sc = 1.f;
    }
    uint4 p;
    p.x = (unsigned)f2bf(v0.x * sc) | ((unsigned)f2bf(v0.y * sc) << 16);
    p.y = (unsigned)f2bf(v0.z * sc) | ((unsigned)f2bf(v0.w * sc) << 16);
    p.z = (unsigned)f2bf(v1.x * sc) | ((unsigned)f2bf(v1.y * sc) << 16);
    p.w = (unsigned)f2bf(v1.z * sc) | ((unsigned)f2bf(v1.w * sc) << 16);
    *((uint4*)(As + r * ASTR + seg * 8)) = p;   // byte off = r*528 + seg*16, 16B aligned
  }

  floatx4 acc[4][4] = {};
  int wid = t >> 6, lane = t & 63;
  int quad = lane >> 4, l15 = lane & 15;

  for (int kc = 0; kc < 8; ++kc) {
    int k0 = kc * 32;
    __syncthreads();   // prior readers done (also orders A staging on kc==0)
    // stage W chunk: Wl[n][0..31] = Wt[n][k0..k0+31]  (already bf16, plain copy)
#pragma unroll
    for (int rep = 0; rep < 4; ++rep) {
      int flat = t + rep * 256;     // 0..1023
      int n = flat >> 2, part = flat & 3;
      *((uint4*)(Wl + n * WSTR + part * 8)) =
          *((const uint4*)(Wt + n * 256 + k0 + part * 8));
    }
    __syncthreads();
    short8 af[4], bfr[4];
#pragma unroll
    for (int mi = 0; mi < 4; ++mi)
      af[mi] = *((const short8*)(As + (mi * 16 + l15) * ASTR + k0 + quad * 8));
#pragma unroll
    for (int ni = 0; ni < 4; ++ni)
      bfr[ni] = *((const short8*)(Wl + (wid * 64 + ni * 16 + l15) * WSTR + quad * 8));
#pragma unroll
    for (int mi = 0; mi < 4; ++mi)
#pragma unroll
      for (int ni = 0; ni < 4; ++ni)
        acc[mi][ni] = __builtin_amdgcn_mfma_f32_16x16x32_bf16(
            af[mi], bfr[ni], acc[mi][ni], 0, 0, 0);
  }

  // epilogue: C/D map col=lane&15, row=quad*4+reg; store bf16
  float bv[4];
#pragma unroll
  for (int ni = 0; ni < 4; ++ni) bv[ni] = b[wid * 64 + ni * 16 + l15];
#pragma unroll
  for (int mi = 0; mi < 4; ++mi) {
    int rbase = row0 + mi * 16 + quad * 4;
#pragma unroll
    for (int r = 0; r < 4; ++r) {
      int row = rbase + r;
      if (row < N_DST1) {
#pragma unroll
        for (int ni = 0; ni < 4; ++ni)
          h[(size_t)row * H_F + wid * 64 + ni * 16 + l15] =
              f2bf(fmaxf(acc[mi][ni][r] + bv[ni], 0.f));
      }
    }
  }
}

// ---------------- layer-2 gather-reduce (bf16 h): one wave per dst ----------------
__global__ __launch_bounds__(256) void reduce2_kernel(
    const unsigned short* __restrict__ h, const int* __restrict__ csr,
    const int* __restrict__ rowptr, const int* __restrict__ cnt,
    float* __restrict__ agg) {
  int w = (blockIdx.x * 256 + threadIdx.x) >> 6;
  if (w >= N_DST2) return;
  int lane = threadIdx.x & 63;
  int start = rowptr[w];
  int n     = cnt[w];
  float4 acc = make_float4(0.f, 0.f, 0.f, 0.f);
  for (int j = 0; j < n; ++j) {
    int s = csr[start + j];
    ushort4 v = *((const ushort4*)(h + (size_t)s * H_F + lane * 4));
    acc.x += bf2f(v.x); acc.y += bf2f(v.y);
    acc.z += bf2f(v.z); acc.w += bf2f(v.w);
  }
  ((float4*)(agg + (size_t)w * H_F))[lane] = acc;
}

// ---------------- layer-2 MFMA GEMM: out = [h|agg/deg] @ [Ws2;Wn2] + b ----------------
// one wave per 16 rows; N=48 (3 tiles of 16); no LDS, A/B frags straight from global
__global__ __launch_bounds__(256) void layer2_mfma_kernel(
    const unsigned short* __restrict__ h,   // bf16 [N_DST1][256] (rows <N_DST2 used)
    const float* __restrict__ agg,          // fp32 [N_DST2][256]
    const int* __restrict__ cnt,
    const unsigned short* __restrict__ Wt2, // bf16 [48][512]
    const float* __restrict__ b, float* __restrict__ out) {
  int t = threadIdx.x;
  int wid = t >> 6, lane = t & 63;
  int quad = lane >> 4, l15 = lane & 15;
  int base = blockIdx.x * 64 + wid * 16;
  if (base >= N_DST2) return;
  int arow = base + l15;                    // this lane's A row
  float inv = 1.f / fmaxf((float)cnt[arow], 1.f);
  floatx4 acc[3] = {};

  // self half: k 0..255 straight from bf16 h
  for (int kc = 0; kc < 8; ++kc) {
    short8 af = *((const short8*)(h + (size_t)arow * H_F + kc * 32 + quad * 8));
#pragma unroll
    for (int nt = 0; nt < 3; ++nt) {
      short8 bf = *((const short8*)(Wt2 + (nt * 16 + l15) * 512 + kc * 32 + quad * 8));
      acc[nt] = __builtin_amdgcn_mfma_f32_16x16x32_bf16(af, bf, acc[nt], 0, 0, 0);
    }
  }
  // neighbor half: k 256..511 from fp32 agg * inv
  for (int kc = 0; kc < 8; ++kc) {
    const float* src = agg + (size_t)arow * H_F + kc * 32 + quad * 8;
    float4 v0 = ((const float4*)src)[0];
    float4 v1 = ((const float4*)src)[1];
    short8 af;
    af[0] = (short)f2bf(v0.x * inv); af[1] = (short)f2bf(v0.y * inv);
    af[2] = (short)f2bf(v0.z * inv); af[3] = (short)f2bf(v0.w * inv);
    af[4] = (short)f2bf(v1.x * inv); af[5] = (short)f2bf(v1.y * inv);
    af[6] = (short)f2bf(v1.z * inv); af[7] = (short)f2bf(v1.w * inv);
#pragma unroll
    for (int nt = 0; nt < 3; ++nt) {
      short8 bf = *((const short8*)(Wt2 + (nt * 16 + l15) * 512 + 256 + kc * 32 + quad * 8));
      acc[nt] = __builtin_amdgcn_mfma_f32_16x16x32_bf16(af, bf, acc[nt], 0, 0, 0);
    }
  }
  // epilogue: col = nt*16 + (lane&15), row = base + quad*4 + r
#pragma unroll
  for (int nt = 0; nt < 3; ++nt) {
    int col = nt * 16 + l15;
    if (col < N_CLS) {
      float bv = b[col];
#pragma unroll
      for (int r = 0; r < 4; ++r) {
        int orow = base + quad * 4 + r;
        out[(size_t)orow * N_CLS + col] = acc[nt][r] + bv;
      }
    }
  }
}

extern "C" void kernel_launch(void* const* d_in, const int* in_sizes, int n_in,
                              void* d_out, int out_size, void* d_ws, size_t ws_size,
                              hipStream_t stream) {
  const float* x   = (const float*)d_in[0];
  const float* Ws1 = (const float*)d_in[1];
  const float* Wn1 = (const float*)d_in[2];
  const float* b1  = (const float*)d_in[3];
  const float* Ws2 = (const float*)d_in[4];
  const float* Wn2 = (const float*)d_in[5];
  const float* b2  = (const float*)d_in[6];
  const int* src1  = (const int*)d_in[7];
  const int* dst1  = (const int*)d_in[8];
  const int* src2  = (const int*)d_in[9];
  const int* dst2  = (const int*)d_in[10];

  int*   wsI  = (int*)d_ws;
  float* wsF  = (float*)d_ws;
  int*   cnt1  = wsI + OFF_CNT1;
  int*   cnt2  = wsI + OFF_CNT2;
  int*   rp1   = wsI + OFF_RP1;
  int*   rp2   = wsI + OFF_RP2;
  int*   fill1 = wsI + OFF_FILL1;
  int*   fill2 = wsI + OFF_FILL2;
  int*   part  = wsI + OFF_PART;
  unsigned short* Wt  = (unsigned short*)(wsI + OFF_WT1);
  unsigned short* Wt2 = (unsigned short*)(wsI + OFF_WT2);
  int*   csr1  = wsI + OFF_CSR1;
  int*   csr2  = wsI + OFF_CSR2;
  float* agg1  = wsF + OFF_AGG1;
  float* agg2  = wsF + OFF_AGG1;   // aliases agg1 (agg1 dead after layer1)
  unsigned short* h = (unsigned short*)(wsI + OFF_H);
  float* out   = (float*)d_out;

  hipMemsetAsync(wsI, 0, (size_t)ZERO_INTS * sizeof(int), stream);

  {
    int blocks = (E1 + 255) / 256;
    hist_kernel<<<blocks, 256, 0, stream>>>(dst1, dst2, cnt1, cnt2);
  }
  scanA_kernel<<<NB_SCAN, 1024, 0, stream>>>(cnt1, part);
  scanB_kernel<<<1, 64, 0, stream>>>(part);
  scanC_kernel<<<NB_SCAN, 1024, 0, stream>>>(cnt1, part, rp1, rp2, fill1, fill2);
  {
    int blocks = (E1 + 255) / 256;
    scatter_kernel<<<blocks, 256, 0, stream>>>(src1, dst1, src2, dst2,
                                               fill1, fill2, csr1, csr2);
  }
  convw_kernel<<<256, 256, 0, stream>>>(Ws1, Wn1, Wt);
  convw2_kernel<<<48, 512, 0, stream>>>(Ws2, Wn2, Wt2);
  {
    int blocks = (N_DST1 * 64 + 255) / 256;
    reduce1_kernel<<<blocks, 256, 0, stream>>>(x, csr1, rp1, cnt1, agg1);
  }
  {
    int blocks = (N_DST1 + 63) / 64;   // 1563
    layer1_mfma_kernel<<<blocks, 256, 0, stream>>>(x, agg1, cnt1, Wt, b1, h);
  }
  {
    int blocks = (N_DST2 * 64 + 255) / 256;
    reduce2_kernel<<<blocks, 256, 0, stream>>>(h, csr2, rp2, cnt2, agg2);
  }
  {
    int blocks = (N_DST2 + 63) / 64;   // 313
    layer2_mfma_kernel<<<blocks, 256, 0, stream>>>(h, agg2, cnt2, Wt2, b2, out);
  }
}